// Round 18
// baseline (136.149 us; speedup 1.0000x reference)
//
#include <hip/hip_runtime.h>

// Problem constants (from reference)
#define NN 4096
#define CC 128
#define II 9
#define DD 9
#define EE 10
#define PP3 23
#define PP2 5
#define PP1 3
// symmetric monomial counts over 9 vars
#define F3 165   // i<=j<=k
#define F2 45    // i<=j
#define F1 9
#define FTOT (F3 + F2 + F1)  // 219
#define FPAD 224             // padded K (14 x 16)
#define NKT14 14             // K-tiles of 16 (32x32x16 MFMA)

// workspace layout (bytes)
#define SU3_ELEMS (F3 * PP3 * DD)              // 34155 floats
#define SU2_ELEMS (F2 * PP2 * DD)              // 2025 floats
#define SU3_OFF 0
#define SU2_OFF (SU3_OFF + SU3_ELEMS * 4)
#define CUR_OFF (SU2_OFF + SU2_ELEMS * 4)
#define LIST_OFF (CUR_OFF + 64)                // 16 ints + pad
#define WG16_OFF (LIST_OFF + NN * EE * 4)      // f16 W images: E*C*9*224*2 = 5.2 MB

#define CPB 16     // channels per block (1 per wave, 16 waves) — 576B aligned chunks
#define TS 16      // tile-stride (grid z) — round-18: 1280 blocks, ~1 tile each
#define SROW 148   // sOut row stride in dwords (16*9=144 used, +4 pad)
#define FDCHUNK 16 // (f,d)-pairs per wprep block

typedef _Float16 f16x8 __attribute__((ext_vector_type(8)));
typedef __fp16 fp16x2 __attribute__((ext_vector_type(2)));   // cvt_pkrtz return type
typedef float f32x16 __attribute__((ext_vector_type(16)));

static __device__ __forceinline__ unsigned pkrtz(float a, float b) {
    fp16x2 h = __builtin_amdgcn_cvt_pkrtz(a, b);
    return __builtin_bit_cast(unsigned, h);
}

static __device__ __forceinline__ unsigned short h16(float a) {
    _Float16 ha = (_Float16)a;
    return __builtin_bit_cast(unsigned short, ha);
}

// Fused: symmetrize u3/u2 (one thread per (t,p,d) output element) + zero
// the bucket cursors (16 spare threads).
__global__ void sym_u_zero_kernel(const float* __restrict__ u3,
                                  const float* __restrict__ u2,
                                  float* __restrict__ su3,
                                  float* __restrict__ su2,
                                  int* __restrict__ cursors) {
    int gid = blockIdx.x * blockDim.x + threadIdx.x;
    if (gid < F3 * PP3 * 9) {
        const int t = gid / (PP3 * 9);
        const int rr = gid % (PP3 * 9);
        const int p = rr / 9;
        const int d = rr % 9;
        int I0 = 0, J0 = 0, K0 = 0;
        {
            int rem = t;
            bool found = false;
            for (int i = 0; i < 9 && !found; i++)
                for (int j = i; j < 9 && !found; j++) {
                    int cnt = 9 - j;
                    if (rem < cnt) { I0 = i; J0 = j; K0 = j + rem; found = true; }
                    else rem -= cnt;
                }
        }
        int a[3] = {I0, J0, K0};
        const int ord[6][3] = {{0,1,2},{0,2,1},{1,0,2},{1,2,0},{2,0,1},{2,1,0}};
        int codes[6];
        int np = 0;
        float s = 0.f;
        for (int q = 0; q < 6; q++) {
            int ii = a[ord[q][0]], jj = a[ord[q][1]], kk = a[ord[q][2]];
            int code = (ii * 9 + jj) * 9 + kk;
            bool seen = false;
            for (int r = 0; r < np; r++) if (codes[r] == code) seen = true;
            if (!seen) {
                codes[np++] = code;
                s += u3[(((((d * 9 + ii) * 9 + jj) * 9 + kk)) * PP3) + p];
            }
        }
        su3[(t * PP3 + p) * 9 + d] = s;
    } else if (gid < F3 * PP3 * 9 + F2 * PP2 * 9) {
        const int g2 = gid - F3 * PP3 * 9;
        const int t = g2 / (PP2 * 9);
        const int rr = g2 % (PP2 * 9);
        const int p = rr / 9;
        const int d = rr % 9;
        int I0 = 0, J0 = 0;
        {
            int rem = t;
            bool found = false;
            for (int i = 0; i < 9 && !found; i++) {
                int cnt = 9 - i;
                if (rem < cnt) { I0 = i; J0 = i + rem; found = true; }
                else rem -= cnt;
            }
        }
        float s = u2[(((d * 9 + I0) * 9 + J0) * PP2) + p];
        if (I0 != J0) s += u2[(((d * 9 + J0) * 9 + I0) * PP2) + p];
        su2[(t * PP2 + p) * 9 + d] = s;
    } else if (gid < F3 * PP3 * 9 + F2 * PP2 * 9 + 16) {
        cursors[gid - (F3 * PP3 * 9 + F2 * PP2 * 9)] = 0;
    }
}

// Atomic append bucketing. List ORDER is nondeterministic, but each node's
// result is a fixed-order dot product independent of its list slot, so
// d_out is bit-deterministic.
__global__ void bucket_kernel(const int* __restrict__ indices,
                              int* __restrict__ cursors,
                              int* __restrict__ lists) {
    int b = blockIdx.x * blockDim.x + threadIdx.x;
    if (b < NN) {
        int e = indices[b];
        int slot = atomicAdd(&cursors[e], 1);
        lists[e * NN + slot] = b;
    }
}

// wprep, round-18 rewrite. Old form: 1280 blocks x 219 threads each doing
// 69 scattered L2 loads (~19M transactions, est ~35us — the hidden cost
// behind the 45us total-minus-main residual since r9). New form: lane = c
// (coalesced/broadcast), wave-uniform (f,d) makes su3[f,p,d] an SGPR load;
// w-tables staged in LDS once per block; 16 (f,d)-pairs per block.
// fd = d*FPAD + f indexes the [9][FPAD] image directly.
__global__ __launch_bounds__(256) void wprep_fast_kernel(
    const float* __restrict__ su3,
    const float* __restrict__ su2,
    const float* __restrict__ u1,
    const float* __restrict__ w3,
    const float* __restrict__ w2,
    const float* __restrict__ w1,
    unsigned short* __restrict__ Wg16)
{
    const int e = blockIdx.y;
    const int fd0 = blockIdx.x * FDCHUNK;
    const int c = threadIdx.x & 127;
    const int sub = threadIdx.x >> 7;   // 0 or 1; wave-uniform

    __shared__ float sW3[PP3 * CC];     // 11.8 KB
    __shared__ float sW2[PP2 * CC];
    __shared__ float sW1[PP1 * CC];
    for (int q = threadIdx.x; q < PP3 * CC; q += 256) sW3[q] = w3[e * PP3 * CC + q];
    for (int q = threadIdx.x; q < PP2 * CC; q += 256) sW2[q] = w2[e * PP2 * CC + q];
    for (int q = threadIdx.x; q < PP1 * CC; q += 256) sW1[q] = w1[e * PP1 * CC + q];
    __syncthreads();

    #pragma unroll
    for (int it = 0; it < FDCHUNK / 2; it++) {
        const int fd = fd0 + it * 2 + sub;
        if (fd >= 9 * FPAD) break;
        const int d = fd / FPAD;        // wave-uniform
        const int f = fd % FPAD;        // wave-uniform
        float v = 0.f;
        if (f < F3) {
            #pragma unroll 1
            for (int p = 0; p < PP3; p++)
                v += su3[(f * PP3 + p) * 9 + d] * sW3[p * CC + c];
        } else if (f < F3 + F2) {
            for (int p = 0; p < PP2; p++)
                v += su2[((f - F3) * PP2 + p) * 9 + d] * sW2[p * CC + c];
        } else if (f < FTOT) {
            for (int p = 0; p < PP1; p++)
                v += u1[(d * 9 + (f - F3 - F2)) * PP1 + p] * sW1[p * CC + c];
        }
        Wg16[(size_t)(e * CC + c) * (9 * FPAD) + fd] = h16(v);
    }
}

// Main kernel, round 18: identical to round 17 (16 ch/block, LDS-staged
// 576B-aligned output) except TS=16 — 1280 blocks, ~1 tile per block.
// r17 lesson: at 640 blocks the kernel was latency-bound with only 2.5
// scheduling rounds and long tails (dur pinned ~60-65us across r14-r17
// while hbm_bytes swung 95-132MB — NOT BW-bound).
__global__ __launch_bounds__(1024, 4) void symcon_reg32_kernel(
    const float* __restrict__ x,
    const unsigned short* __restrict__ Wg16,
    const int* __restrict__ cursors,
    const int* __restrict__ lists,
    float* __restrict__ out)
{
    const int e = blockIdx.y;
    const int lane = threadIdx.x & 63;
    const int wid = threadIdx.x >> 6;          // 0..15 = channel within block
    const int c = blockIdx.x * CPB + wid;
    const int r = lane & 31;       // node row within tile; also B col (= d)
    const int g = lane >> 5;       // k-half
    const bool isg1 = (g == 1);

    const int cnt = cursors[e];
    const int ntiles = (cnt + 31) >> 5;
    if ((int)blockIdx.z >= ntiles) return;   // uniform early exit

    __shared__ __align__(16) float sOut[32 * SROW];   // [node][16ch x 9d + pad]
    __shared__ int sNid[32];

    // B fragments: lane holds B[k = t*16 + g*8 + j][col = r], zeros for col>=9
    f16x8 bfrag[NKT14];
    {
        const unsigned short* wp = Wg16 + (size_t)(e * CC + c) * (9 * FPAD);
        #pragma unroll
        for (int t = 0; t < NKT14; t++) {
            f16x8 v = {0, 0, 0, 0, 0, 0, 0, 0};
            if (r < 9)
                v = *reinterpret_cast<const f16x8*>(wp + r * FPAD + t * 16 + g * 8);
            bfrag[t] = v;
        }
    }

    const int* lbase = lists + e * NN;

    int T = blockIdx.z;
    int nb_cur, nb_next;
    float xv[9];
    {
        const int n = T * 32 + r;
        const bool valid = (n < cnt);
        nb_cur = valid ? lbase[n] : 0;
        const float* xr = x + ((size_t)nb_cur * CC + c) * II;
        #pragma unroll
        for (int q = 0; q < 9; q++) xv[q] = valid ? xr[q] : 0.f;
    }
    {
        const int n = (T + TS) * 32 + r;
        const bool valid = (T + TS < ntiles) && (n < cnt);
        nb_next = valid ? lbase[n] : 0;
    }

    while (T < ntiles) {
        // node ids for this tile (threads 0..31 are wave 0 lanes r=0..31)
        if (threadIdx.x < 32) sNid[threadIdx.x] = nb_cur;

        // ---- independent prefetches: x row for T+TS (id already in hand),
        //      id for T+2*TS ----
        float xn[9];
        {
            const int n = (T + TS) * 32 + r;
            const bool valid = (T + TS < ntiles) && (n < cnt);
            const float* xr = x + ((size_t)nb_next * CC + c) * II;
            #pragma unroll
            for (int q = 0; q < 9; q++) xn[q] = valid ? xr[q] : 0.f;
        }
        int nb_next2;
        {
            const int n = (T + 2 * TS) * 32 + r;
            const bool valid = (T + 2 * TS < ntiles) && (n < cnt);
            nb_next2 = valid ? lbase[n] : 0;
        }

        // ---- monomial stream with interleaved MFMA ----
        f32x16 acc = {0.f, 0.f, 0.f, 0.f, 0.f, 0.f, 0.f, 0.f,
                      0.f, 0.f, 0.f, 0.f, 0.f, 0.f, 0.f, 0.f};
        unsigned au[4];
        {
            float pend = 0.f;
            int F = 0;
            // Pair P = F>>1: K-tile t = P>>3, q = P&7, dword jd = q&3 — all
            // compile-time after unroll. q<4 writes unconditional (g1 lanes
            // overwritten by their q>=4 select). At q==7 fragment complete
            // -> MFMA.
#define EMITR(expr) { const float _m = (expr);                                \
            if (F & 1) { const unsigned _pk = pkrtz(pend, _m);                \
                const int _P = F >> 1; const int _t = _P >> 3;                \
                const int _q = _P & 7; const int _jd = _q & 3;                \
                if (_q < 4) au[_jd] = _pk;                                    \
                else        au[_jd] = isg1 ? _pk : au[_jd];                   \
                if (_q == 7) {                                                \
                    f16x8 af;                                                 \
                    unsigned* _ap = reinterpret_cast<unsigned*>(&af);         \
                    _ap[0] = au[0]; _ap[1] = au[1];                           \
                    _ap[2] = au[2]; _ap[3] = au[3];                           \
                    acc = __builtin_amdgcn_mfma_f32_32x32x16_f16(             \
                        af, bfrag[_t], acc, 0, 0, 0);                         \
                }                                                             \
            } else pend = _m; F++; }
            #pragma unroll
            for (int i = 0; i < 9; i++)
                #pragma unroll
                for (int j = i; j < 9; j++) {
                    const float xij = xv[i] * xv[j];
                    #pragma unroll
                    for (int k = j; k < 9; k++)
                        EMITR(xij * xv[k])
                }
            #pragma unroll
            for (int i = 0; i < 9; i++)
                #pragma unroll
                for (int j = i; j < 9; j++)
                    EMITR(xv[i] * xv[j])
            #pragma unroll
            for (int i = 0; i < 9; i++)
                EMITR(xv[i])
            #pragma unroll
            for (int z = 0; z < 5; z++)   // zero-pad f 219..223 (exactly 224)
                EMITR(0.f)
#undef EMITR
        }

        // ---- stage D tile into LDS: row = (reg&3)+8*(reg>>2)+4*g,
        //      dword = wid*9 + r (channel-major within node row) ----
        if (r < 9) {
            #pragma unroll
            for (int reg = 0; reg < 16; reg++) {
                const int row = (reg & 3) + 8 * (reg >> 2) + 4 * g;
                sOut[row * SROW + wid * 9 + r] = acc[reg];
            }
        }
        __syncthreads();

        // ---- coalesced store: 36 float4 per node = 576B line-aligned ----
        for (int q = threadIdx.x; q < 32 * 36; q += 1024) {
            const int node = q / 36;
            const int f4 = q % 36;
            if (T * 32 + node < cnt) {
                const float4 v = *reinterpret_cast<const float4*>(&sOut[node * SROW + f4 * 4]);
                float4* gp = reinterpret_cast<float4*>(
                    out + (size_t)sNid[node] * (CC * DD) + blockIdx.x * (CPB * DD));
                gp[f4] = v;
            }
        }
        __syncthreads();

        #pragma unroll
        for (int q = 0; q < 9; q++) xv[q] = xn[q];
        nb_cur = nb_next;
        nb_next = nb_next2;
        T += TS;
    }
}

extern "C" void kernel_launch(void* const* d_in, const int* in_sizes, int n_in,
                              void* d_out, int out_size, void* d_ws, size_t ws_size,
                              hipStream_t stream) {
    const float* x   = (const float*)d_in[0];
    const int* indices = (const int*)d_in[1];
    const float* u3  = (const float*)d_in[2];
    const float* u2  = (const float*)d_in[3];
    const float* u1  = (const float*)d_in[4];
    const float* w3  = (const float*)d_in[5];
    const float* w2  = (const float*)d_in[6];
    const float* w1  = (const float*)d_in[7];
    float* out = (float*)d_out;

    char* ws = (char*)d_ws;
    float* su3 = (float*)(ws + SU3_OFF);
    float* su2 = (float*)(ws + SU2_OFF);
    int* cursors = (int*)(ws + CUR_OFF);
    int* lists = (int*)(ws + LIST_OFF);
    unsigned short* Wg16 = (unsigned short*)(ws + WG16_OFF);

    const int symn = F3 * PP3 * 9 + F2 * PP2 * 9 + 16;
    hipLaunchKernelGGL(sym_u_zero_kernel, dim3((symn + 255) / 256), dim3(256), 0, stream,
                       u3, u2, su3, su2, cursors);
    hipLaunchKernelGGL(bucket_kernel, dim3((NN + 255) / 256), dim3(256), 0, stream,
                       indices, cursors, lists);
    hipLaunchKernelGGL(wprep_fast_kernel, dim3((9 * FPAD + FDCHUNK - 1) / FDCHUNK, EE),
                       dim3(256), 0, stream, su3, su2, u1, w3, w2, w1, Wg16);
    hipLaunchKernelGGL(symcon_reg32_kernel, dim3(CC / CPB, EE, TS), dim3(1024), 0, stream,
                       x, Wg16, cursors, lists, out);
}

// Round 19
// 103.259 us; speedup vs baseline: 1.3185x; 1.3185x over previous
//
#include <hip/hip_runtime.h>

// Problem constants (from reference)
#define NN 4096
#define CC 128
#define II 9
#define DD 9
#define EE 10
#define PP3 23
#define PP2 5
#define PP1 3
// symmetric monomial counts over 9 vars
#define F3 165   // i<=j<=k
#define F2 45    // i<=j
#define F1 9
#define FTOT (F3 + F2 + F1)  // 219
#define FPAD 224             // padded K (14 x 16)
#define NKT14 14             // K-tiles of 16 (32x32x16 MFMA)

// workspace layout (bytes)
#define SU3_ELEMS (F3 * PP3 * DD)              // 34155 floats
#define SU2_ELEMS (F2 * PP2 * DD)              // 2025 floats
#define SU3_OFF 0
#define SU2_OFF (SU3_OFF + SU3_ELEMS * 4)
#define CUR_OFF (SU2_OFF + SU2_ELEMS * 4)
#define LIST_OFF (CUR_OFF + 64)                // 16 ints + pad
#define WG16_OFF (LIST_OFF + NN * EE * 4)      // f16 W images: E*C*9*224*2 = 5.2 MB

#define CPB 4      // channels per block (1 per wave) — r14 best-known config
#define TS 8       // tile-stride (grid z) — 2560 blocks
#define WFD 64     // fd-chunk per wprep block (64 fd = 128B = 2 lines per c)
#define SYMN (F3 * PP3 * 9 + F2 * PP2 * 9)     // 36180
#define SYMBLK ((SYMN + 255) / 256)            // 142

typedef _Float16 f16x8 __attribute__((ext_vector_type(8)));
typedef __fp16 fp16x2 __attribute__((ext_vector_type(2)));   // cvt_pkrtz return type
typedef float f32x16 __attribute__((ext_vector_type(16)));

static __device__ __forceinline__ unsigned pkrtz(float a, float b) {
    fp16x2 h = __builtin_amdgcn_cvt_pkrtz(a, b);
    return __builtin_bit_cast(unsigned, h);
}

static __device__ __forceinline__ unsigned short h16(float a) {
    _Float16 ha = (_Float16)a;
    return __builtin_bit_cast(unsigned short, ha);
}

// Fused prep kernel: blocks [0, SYMBLK) symmetrize u3/u2; blocks
// [SYMBLK, SYMBLK+16) bucket nodes by species (cursors pre-zeroed by
// hipMemsetAsync; the two jobs are mutually independent).
__global__ void prep_kernel(const float* __restrict__ u3,
                            const float* __restrict__ u2,
                            float* __restrict__ su3,
                            float* __restrict__ su2,
                            const int* __restrict__ indices,
                            int* __restrict__ cursors,
                            int* __restrict__ lists) {
    if (blockIdx.x < SYMBLK) {
        const int gid = blockIdx.x * 256 + threadIdx.x;
        if (gid < F3 * PP3 * 9) {
            const int t = gid / (PP3 * 9);
            const int rr = gid % (PP3 * 9);
            const int p = rr / 9;
            const int d = rr % 9;
            int I0 = 0, J0 = 0, K0 = 0;
            {
                int rem = t;
                bool found = false;
                for (int i = 0; i < 9 && !found; i++)
                    for (int j = i; j < 9 && !found; j++) {
                        int cnt = 9 - j;
                        if (rem < cnt) { I0 = i; J0 = j; K0 = j + rem; found = true; }
                        else rem -= cnt;
                    }
            }
            int a[3] = {I0, J0, K0};
            const int ord[6][3] = {{0,1,2},{0,2,1},{1,0,2},{1,2,0},{2,0,1},{2,1,0}};
            int codes[6];
            int np = 0;
            float s = 0.f;
            for (int q = 0; q < 6; q++) {
                int ii = a[ord[q][0]], jj = a[ord[q][1]], kk = a[ord[q][2]];
                int code = (ii * 9 + jj) * 9 + kk;
                bool seen = false;
                for (int r = 0; r < np; r++) if (codes[r] == code) seen = true;
                if (!seen) {
                    codes[np++] = code;
                    s += u3[(((((d * 9 + ii) * 9 + jj) * 9 + kk)) * PP3) + p];
                }
            }
            su3[(t * PP3 + p) * 9 + d] = s;
        } else if (gid < SYMN) {
            const int g2 = gid - F3 * PP3 * 9;
            const int t = g2 / (PP2 * 9);
            const int rr = g2 % (PP2 * 9);
            const int p = rr / 9;
            const int d = rr % 9;
            int I0 = 0, J0 = 0;
            {
                int rem = t;
                bool found = false;
                for (int i = 0; i < 9 && !found; i++) {
                    int cnt = 9 - i;
                    if (rem < cnt) { I0 = i; J0 = i + rem; found = true; }
                    else rem -= cnt;
                }
            }
            float s = u2[(((d * 9 + I0) * 9 + J0) * PP2) + p];
            if (I0 != J0) s += u2[(((d * 9 + J0) * 9 + I0) * PP2) + p];
            su2[(t * PP2 + p) * 9 + d] = s;
        }
    } else {
        const int b = (blockIdx.x - SYMBLK) * 256 + threadIdx.x;
        if (b < NN) {
            const int e = indices[b];
            const int slot = atomicAdd(&cursors[e], 1);
            lists[e * NN + slot] = b;
        }
    }
}

// wprep v3. Lane = c (w-tables LDS-broadcast), wave-uniform (f,d) makes
// su reads broadcast loads of the L2-hot su3/su2. Output staged in padded
// LDS then written TRANSPOSED back to the [e][c][fd] layout as 32
// consecutive dwords per c = 2 full aligned 64B lines (fd0 % 64 == 0 and
// the per-c image stride 4032B = 63 lines) — zero write amplification.
// r18 lesson: the previous version wrote 2B at 4032B stride = 128 lines
// per store instruction (~32x write amplification on the W image).
__global__ __launch_bounds__(256) void wprep_v3_kernel(
    const float* __restrict__ su3,
    const float* __restrict__ su2,
    const float* __restrict__ u1,
    const float* __restrict__ w3,
    const float* __restrict__ w2,
    const float* __restrict__ w1,
    unsigned short* __restrict__ Wg16)
{
    const int e = blockIdx.y;
    const int fd0 = blockIdx.x * WFD;
    const int c = threadIdx.x & 127;
    const int sub = threadIdx.x >> 7;   // wave-uniform (waves 0,1 -> 0; 2,3 -> 1)

    __shared__ float sW3[PP3 * CC];
    __shared__ float sW2[PP2 * CC];
    __shared__ float sW1[PP1 * CC];
    __shared__ unsigned short sT[CC * 66];   // [c][64 fd] padded to 66 (bank skew)

    for (int q = threadIdx.x; q < PP3 * CC; q += 256) sW3[q] = w3[e * PP3 * CC + q];
    for (int q = threadIdx.x; q < PP2 * CC; q += 256) sW2[q] = w2[e * PP2 * CC + q];
    for (int q = threadIdx.x; q < PP1 * CC; q += 256) sW1[q] = w1[e * PP1 * CC + q];
    __syncthreads();

    #pragma unroll
    for (int it = 0; it < WFD / 2; it++) {
        const int l = it * 2 + sub;
        const int fd = fd0 + l;
        const int d = fd / FPAD;
        const int f = fd - d * FPAD;
        float v = 0.f;
        if (d < 9) {
            if (f < F3) {
                #pragma unroll
                for (int p = 0; p < PP3; p++)
                    v += su3[(f * PP3 + p) * 9 + d] * sW3[p * CC + c];
            } else if (f < F3 + F2) {
                #pragma unroll
                for (int p = 0; p < PP2; p++)
                    v += su2[((f - F3) * PP2 + p) * 9 + d] * sW2[p * CC + c];
            } else if (f < FTOT) {
                #pragma unroll
                for (int p = 0; p < PP1; p++)
                    v += u1[(d * 9 + (f - F3 - F2)) * PP1 + p] * sW1[p * CC + c];
            }
        }
        sT[c * 66 + l] = h16(v);
    }
    __syncthreads();

    // coalesced transposed store: 32 dwords (64 fd) per c, full lines
    unsigned* dst = reinterpret_cast<unsigned*>(Wg16);
    for (int q = threadIdx.x; q < CC * 32; q += 256) {
        const int cc = q >> 5;
        const int dw = q & 31;
        if (fd0 + dw * 2 < 9 * FPAD) {
            const unsigned lo = sT[cc * 66 + dw * 2];
            const unsigned hi = sT[cc * 66 + dw * 2 + 1];
            dst[(size_t)(e * CC + cc) * (9 * FPAD / 2) + fd0 / 2 + dw] = lo | (hi << 16);
        }
    }
}

// Main kernel — byte-identical to round 14 (best measured: 58us, absmax
// 0.125): CPB=4, TS=8, 32x32x16 MFMA, barrier/LDS-free, shfl-scatter,
// 2-deep software pipeline.
__global__ __launch_bounds__(256, 4) void symcon_reg32_kernel(
    const float* __restrict__ x,
    const unsigned short* __restrict__ Wg16,
    const int* __restrict__ cursors,
    const int* __restrict__ lists,
    float* __restrict__ out)
{
    const int e = blockIdx.y;
    const int lane = threadIdx.x & 63;
    const int wid = threadIdx.x >> 6;
    const int c = blockIdx.x * CPB + wid;
    const int r = lane & 31;       // node row within tile; also B col (= d)
    const int g = lane >> 5;       // k-half
    const bool isg1 = (g == 1);

    // B fragments: lane holds B[k = t*16 + g*8 + j][col = r], zeros for col>=9
    f16x8 bfrag[NKT14];
    {
        const unsigned short* wp = Wg16 + (size_t)(e * CC + c) * (9 * FPAD);
        #pragma unroll
        for (int t = 0; t < NKT14; t++) {
            f16x8 v = {0, 0, 0, 0, 0, 0, 0, 0};
            if (r < 9)
                v = *reinterpret_cast<const f16x8*>(wp + r * FPAD + t * 16 + g * 8);
            bfrag[t] = v;
        }
    }

    const int cnt = cursors[e];
    const int ntiles = (cnt + 31) >> 5;
    const int* lbase = lists + e * NN;
    float* outc = out + (size_t)c * DD;

    int T = blockIdx.z;
    int nb_cur, nb_next;
    float xv[9];
    {
        const int n = T * 32 + r;
        const bool valid = (T < ntiles) && (n < cnt);
        nb_cur = valid ? lbase[n] : 0;
        const float* xr = x + ((size_t)nb_cur * CC + c) * II;
        #pragma unroll
        for (int q = 0; q < 9; q++) xv[q] = valid ? xr[q] : 0.f;
    }
    {
        const int n = (T + TS) * 32 + r;
        const bool valid = (T + TS < ntiles) && (n < cnt);
        nb_next = valid ? lbase[n] : 0;
    }

    while (T < ntiles) {
        // ---- independent prefetches: x row for T+TS (id already in hand),
        //      id for T+2*TS ----
        float xn[9];
        {
            const int n = (T + TS) * 32 + r;
            const bool valid = (T + TS < ntiles) && (n < cnt);
            const float* xr = x + ((size_t)nb_next * CC + c) * II;
            #pragma unroll
            for (int q = 0; q < 9; q++) xn[q] = valid ? xr[q] : 0.f;
        }
        int nb_next2;
        {
            const int n = (T + 2 * TS) * 32 + r;
            const bool valid = (T + 2 * TS < ntiles) && (n < cnt);
            nb_next2 = valid ? lbase[n] : 0;
        }

        // ---- monomial stream with interleaved MFMA ----
        f32x16 acc = {0.f, 0.f, 0.f, 0.f, 0.f, 0.f, 0.f, 0.f,
                      0.f, 0.f, 0.f, 0.f, 0.f, 0.f, 0.f, 0.f};
        unsigned au[4];
        {
            float pend = 0.f;
            int F = 0;
            // Pair P = F>>1: K-tile t = P>>3, q = P&7, dword jd = q&3 — all
            // compile-time after unroll. q<4 writes unconditional (g1 lanes
            // overwritten by their q>=4 select). At q==7 fragment complete
            // -> MFMA.
#define EMITR(expr) { const float _m = (expr);                                \
            if (F & 1) { const unsigned _pk = pkrtz(pend, _m);                \
                const int _P = F >> 1; const int _t = _P >> 3;                \
                const int _q = _P & 7; const int _jd = _q & 3;                \
                if (_q < 4) au[_jd] = _pk;                                    \
                else        au[_jd] = isg1 ? _pk : au[_jd];                   \
                if (_q == 7) {                                                \
                    f16x8 af;                                                 \
                    unsigned* _ap = reinterpret_cast<unsigned*>(&af);         \
                    _ap[0] = au[0]; _ap[1] = au[1];                           \
                    _ap[2] = au[2]; _ap[3] = au[3];                           \
                    acc = __builtin_amdgcn_mfma_f32_32x32x16_f16(             \
                        af, bfrag[_t], acc, 0, 0, 0);                         \
                }                                                             \
            } else pend = _m; F++; }
            #pragma unroll
            for (int i = 0; i < 9; i++)
                #pragma unroll
                for (int j = i; j < 9; j++) {
                    const float xij = xv[i] * xv[j];
                    #pragma unroll
                    for (int k = j; k < 9; k++)
                        EMITR(xij * xv[k])
                }
            #pragma unroll
            for (int i = 0; i < 9; i++)
                #pragma unroll
                for (int j = i; j < 9; j++)
                    EMITR(xv[i] * xv[j])
            #pragma unroll
            for (int i = 0; i < 9; i++)
                EMITR(xv[i])
            #pragma unroll
            for (int z = 0; z < 5; z++)   // zero-pad f 219..223 (exactly 224)
                EMITR(0.f)
#undef EMITR
        }

        // ---- scatter D: col = r (= d), row = (reg&3) + 8*(reg>>2) + 4*g.
        // Node id for row comes from lane 'row' via shfl (all lanes
        // participate; store guarded afterwards). ----
        #pragma unroll
        for (int reg = 0; reg < 16; reg++) {
            const int row = (reg & 3) + 8 * (reg >> 2) + 4 * g;
            const int sb = __shfl(nb_cur, row);
            const int slot = T * 32 + row;
            if (r < 9 && slot < cnt)
                outc[(size_t)sb * (CC * DD) + r] = acc[reg];
        }

        #pragma unroll
        for (int q = 0; q < 9; q++) xv[q] = xn[q];
        nb_cur = nb_next;
        nb_next = nb_next2;
        T += TS;
    }
}

extern "C" void kernel_launch(void* const* d_in, const int* in_sizes, int n_in,
                              void* d_out, int out_size, void* d_ws, size_t ws_size,
                              hipStream_t stream) {
    const float* x   = (const float*)d_in[0];
    const int* indices = (const int*)d_in[1];
    const float* u3  = (const float*)d_in[2];
    const float* u2  = (const float*)d_in[3];
    const float* u1  = (const float*)d_in[4];
    const float* w3  = (const float*)d_in[5];
    const float* w2  = (const float*)d_in[6];
    const float* w1  = (const float*)d_in[7];
    float* out = (float*)d_out;

    char* ws = (char*)d_ws;
    float* su3 = (float*)(ws + SU3_OFF);
    float* su2 = (float*)(ws + SU2_OFF);
    int* cursors = (int*)(ws + CUR_OFF);
    int* lists = (int*)(ws + LIST_OFF);
    unsigned short* Wg16 = (unsigned short*)(ws + WG16_OFF);

    hipMemsetAsync(cursors, 0, 64, stream);
    hipLaunchKernelGGL(prep_kernel, dim3(SYMBLK + (NN + 255) / 256), dim3(256), 0, stream,
                       u3, u2, su3, su2, indices, cursors, lists);
    hipLaunchKernelGGL(wprep_v3_kernel, dim3((9 * FPAD + WFD - 1) / WFD, EE),
                       dim3(256), 0, stream, su3, su2, u1, w3, w2, w1, Wg16);
    hipLaunchKernelGGL(symcon_reg32_kernel, dim3(CC / CPB, EE, TS), dim3(256), 0, stream,
                       x, Wg16, cursors, lists, out);
}